// Round 11
// baseline (115.927 us; speedup 1.0000x reference)
//
#include <hip/hip_runtime.h>
#include <hip/hip_bf16.h>

// B=4, Q=K=512, D=512, H=256
#define HH 256
#define DD 512
#define MM 2048                       // B*Q == B*K flattened rows
#define CSCALE 2.8853900817779268f    // 2*log2(e), folded into W (linear)

typedef __bf16 bf16x8 __attribute__((ext_vector_type(8)));
typedef float floatx4 __attribute__((ext_vector_type(4)));
typedef float float2v __attribute__((ext_vector_type(2)));

// ---------------------------------------------------------------------------
// prep: (a) blocks 0..255: transpose+scale Wq,Wk -> Wt[2][256][512] bf16
//       (b) block 256: wv2 = -2*wv, sumW = sum(wv)
//       (c) blocks 257..1280: convert queries||keys f32 -> Xbf bf16 [2M]
// ---------------------------------------------------------------------------
__global__ __launch_bounds__(256) void prep_kernel(
    const float* __restrict__ Wq, const float* __restrict__ Wk,
    const float* __restrict__ wv,
    const float* __restrict__ queries, const float* __restrict__ keys,
    __bf16* __restrict__ Wt, __bf16* __restrict__ Xbf,
    float* __restrict__ wv2, float* __restrict__ sumWp)
{
  const int bx = blockIdx.x;
  if (bx < 256) {
    const int mat  = bx >> 7;
    const int tile = bx & 127;
    const int kt = tile & 15;    // 512/32 k-tiles
    const int nt = tile >> 4;    // 256/32 n-tiles
    const float* __restrict__ W = mat ? Wk : Wq;
    __bf16* __restrict__ Wo = Wt + (size_t)mat * HH * DD;
    __shared__ float lds[32][33];
    const int i = threadIdx.x >> 5;   // 0..7
    const int j = threadIdx.x & 31;   // 0..31
    const int k0 = kt * 32, n0 = nt * 32;
#pragma unroll
    for (int p = 0; p < 4; ++p)
      lds[i + p * 8][j] = W[(k0 + i + p * 8) * HH + n0 + j];
    __syncthreads();
#pragma unroll
    for (int p = 0; p < 4; ++p) {
      const int n = i + p * 8;
      Wo[(n0 + n) * DD + k0 + j] = (__bf16)(lds[j][n] * CSCALE);
    }
  } else if (bx == 256) {
    __shared__ float red[256];
    const int t = threadIdx.x;
    float w = wv[t];
    wv2[t] = -2.0f * w;
    red[t] = w;
    __syncthreads();
    for (int s = 128; s > 0; s >>= 1) {
      if (t < s) red[t] += red[t + s];
      __syncthreads();
    }
    if (t == 0) *sumWp = red[0];
  } else {
    const int blk = bx - 257;                       // 0..1023
    const size_t dst = (size_t)blk * 2048 + threadIdx.x * 8;
    const float* __restrict__ src =
        (blk < 512) ? (queries + dst) : (keys + dst - (size_t)1048576);
    float4 a = *(const float4*)(src);
    float4 b = *(const float4*)(src + 4);
    bf16x8 v;
    v[0] = (__bf16)a.x; v[1] = (__bf16)a.y; v[2] = (__bf16)a.z; v[3] = (__bf16)a.w;
    v[4] = (__bf16)b.x; v[5] = (__bf16)b.y; v[6] = (__bf16)b.z; v[7] = (__bf16)b.w;
    *(bf16x8*)(Xbf + dst) = v;
  }
}

// ---------------------------------------------------------------------------
// proj: P = Xbf(2048x512 bf16) @ Wt^T (bf16, prescaled by 2*log2e).
// Block = 4 waves: wave (tw, ks) computes 16x32 tile tw over K-half ks.
// LDS combine, then exp2 epilogue:
//   z==0: queries -> eq = exp2(qc) f32 [2048][256]
//   z==1: keys    -> ekd = exp2(kc) f32 DUPLICATED pairs (v,v), layout
//         [m/16][hq(64)][m%16][4 pairs]: 512 B per (tile,hq) group ->
//         score reads 2x dwordx4 per quad, zero unpack, pk-ready splats
// Fragment layouts (HW-verified rounds 1-10):
//   A: lane A[m=lane&15][k=(lane>>4)*8+j]; B: B[k=(lane>>4)*8+j][n=lane&15]
//   D: reg i -> row=(lane>>4)*4+i, col=lane&15
// ---------------------------------------------------------------------------
__global__ __launch_bounds__(256, 4) void proj_kernel(
    const __bf16* __restrict__ Xbf, const __bf16* __restrict__ Wt,
    float* __restrict__ eqp, float2* __restrict__ ekd)
{
  const int w    = threadIdx.x >> 6;
  const int lane = threadIdx.x & 63;
  const int quad = lane >> 4;
  const int r    = lane & 15;
  const int tw = w & 1;        // which 16-row tile
  const int ks = w >> 1;       // which K half
  const bool is_k = (blockIdx.z != 0);
  const __bf16* __restrict__ X  = Xbf + (is_k ? (size_t)1048576 : 0);
  const __bf16* __restrict__ Wb = Wt + (is_k ? (size_t)HH * DD : 0);

  const int m0 = blockIdx.x * 32 + tw * 16;
  const int n0 = blockIdx.y * 32;

  floatx4 acc0 = {0.f, 0.f, 0.f, 0.f};
  floatx4 acc1 = {0.f, 0.f, 0.f, 0.f};
  const __bf16* arow = X + (size_t)(m0 + r) * DD + ks * 256 + quad * 8;
  const __bf16* b0   = Wb + (size_t)(n0 + r) * DD + ks * 256 + quad * 8;
  const __bf16* b1   = b0 + 16 * DD;

#pragma unroll
  for (int kk = 0; kk < 256; kk += 32) {
    bf16x8 af  = *(const bf16x8*)(arow + kk);
    bf16x8 bf0 = *(const bf16x8*)(b0 + kk);
    bf16x8 bf1 = *(const bf16x8*)(b1 + kk);
    acc0 = __builtin_amdgcn_mfma_f32_16x16x32_bf16(af, bf0, acc0, 0, 0, 0);
    acc1 = __builtin_amdgcn_mfma_f32_16x16x32_bf16(af, bf1, acc1, 0, 0, 0);
  }

  __shared__ float part[2][64][9];   // +1 pad: conflict-free combine
  if (ks == 1) {
#pragma unroll
    for (int i = 0; i < 4; ++i) {
      part[tw][lane][i]     = acc0[i];
      part[tw][lane][4 + i] = acc1[i];
    }
  }
  __syncthreads();
  if (ks == 0) {
#pragma unroll
    for (int i = 0; i < 4; ++i) {
      acc0[i] += part[tw][lane][i];
      acc1[i] += part[tw][lane][4 + i];
    }
    const int mrow = m0 + quad * 4;
    if (!is_k) {
#pragma unroll
      for (int i = 0; i < 4; ++i) {
        eqp[(size_t)(mrow + i) * HH + n0 + r] =
            __builtin_amdgcn_exp2f(acc0[i]);
        eqp[(size_t)(mrow + i) * HH + n0 + 16 + r] =
            __builtin_amdgcn_exp2f(acc1[i]);
      }
    } else {
      const int na = n0 + r, nb = n0 + 16 + r;
#pragma unroll
      for (int i = 0; i < 4; ++i) {
        const int m = mrow + i;
        float va = __builtin_amdgcn_exp2f(acc0[i]);
        float vb = __builtin_amdgcn_exp2f(acc1[i]);
        ekd[(((size_t)(m >> 4) * 64 + (na >> 2)) * 16 + (m & 15)) * 4 + (na & 3)] =
            make_float2(va, va);
        ekd[(((size_t)(m >> 4) * 64 + (nb >> 2)) * 16 + (m & 15)) * 4 + (nb & 3)] =
            make_float2(vb, vb);
      }
    }
  }
}

// ---------------------------------------------------------------------------
// score (R11): packed-fp32 rational pairing, packed ACROSS q-rows so every
// op is element-wise (no horizontal ops — the R4 trap). Per q (element):
//   u_i = 1 + eq_i*ek_i; out += [n01*p23 + n23*p01] * rcp(p01*p23)
//   n01 = w'0*u1 + w'1*u0; w' = -2*wv   (exact tanh algebra, 1 rcp / 4 h)
// Operand prep for clean v_pk codegen (all VGPR-resident):
//   eq staged TRANSPOSED in LDS [h][q0..q3] (1 b128 serves both q-pairs)
//   wv staged DUPLICATED (w,w) pairs (b128 = two splats, no v_movs)
//   ek pre-duplicated f32 pairs in ws (proj epilogue), 2 dwordx4 per quad
// 28 pk + 4 trans + 2 glb + 6 ds per 16 wave-terms ~= 6.1 issue-cyc/term
// (was ~10). h-split 512-thr blocks, LDS combine (R10 structure).
// Grid (2,128,4) x 512 = 4 blocks/CU -> 8 waves/SIMD.
// ---------------------------------------------------------------------------
__device__ __forceinline__ float2v pkfma(float2v a, float2v b, float2v c) {
  return __builtin_elementwise_fma(a, b, c);
}
__device__ __forceinline__ float2v lo2(float4 v) { return (float2v){v.x, v.y}; }
__device__ __forceinline__ float2v hi2(float4 v) { return (float2v){v.z, v.w}; }

// one h-quad for one q-pair (2 q-rows packed): 14 pk + 2 trans / 8 terms
__device__ __forceinline__ float2v quad_pair(
    float2v e0, float2v e1, float2v e2, float2v e3,
    float2v k0, float2v k1, float2v k2, float2v k3,
    float2v w0, float2v w1, float2v w2, float2v w3,
    float2v acc)
{
  const float2v one = {1.0f, 1.0f};
  float2v U0 = pkfma(e0, k0, one);
  float2v U1 = pkfma(e1, k1, one);
  float2v U2 = pkfma(e2, k2, one);
  float2v U3 = pkfma(e3, k3, one);
  float2v P01 = U0 * U1;
  float2v P23 = U2 * U3;
  float2v N01 = pkfma(U0, w1, U1 * w0);
  float2v N23 = pkfma(U2, w3, U3 * w2);
  float2v N   = pkfma(N23, P01, N01 * P23);
  float2v D   = P01 * P23;
  float2v R   = {__builtin_amdgcn_rcpf(D.x), __builtin_amdgcn_rcpf(D.y)};
  return pkfma(N, R, acc);
}

__global__ __launch_bounds__(512, 8) void score_kernel(
    const float* __restrict__ eqp, const float4* __restrict__ ekd,
    const float* __restrict__ wv2, const float* __restrict__ sumWp,
    float* __restrict__ out)
{
  __shared__ __align__(16) float  eqt[2][128][4];  // [hb][h][q0..q3] 4 KB
  __shared__ __align__(16) float2 wvd[2][128];     // (w,w) splat pairs 2 KB
  __shared__ __align__(16) float  part[4][256];    // hb=1 partials 4 KB

  const int tid = threadIdx.x;
  const int t   = tid & 255;          // k lane
  const int hb  = tid >> 8;           // h half (waves 0-3 / 4-7)
  const int b   = blockIdx.z;
  const int k   = blockIdx.x * 256 + t;
  const int q0  = blockIdx.y * 4;

  // Stage: eq 4 rows x 256 h, transposed into [h][q]; wv2 duplicated.
  {
    const int c = tid & 255;          // h column
    const int r0 = tid >> 8;          // rows 0,1
    const int r1 = r0 + 2;            // rows 2,3
    float v0 = eqp[(size_t)(b * 512 + q0 + r0) * HH + c];
    float v1 = eqp[(size_t)(b * 512 + q0 + r1) * HH + c];
    eqt[c >> 7][c & 127][r0] = v0;
    eqt[c >> 7][c & 127][r1] = v1;
    if (tid < 256) {
      float w = wv2[tid];
      wvd[tid >> 7][tid & 127] = make_float2(w, w);
    }
  }
  __syncthreads();

  const int m = b * 512 + k;          // global key row in [0,2048)
  // float4-unit base: per (tile,hq) group = 32 float4; lane slot = (m&15)*2
  const float4* __restrict__ kbase =
      ekd + ((size_t)(m >> 4) * 64 + hb * 32) * 32 + (m & 15) * 2;

  float2v accA01 = {0.f, 0.f}, accA23 = {0.f, 0.f};  // (q0,q1),(q2,q3)

  for (int c = 0; c < 16; ++c) {      // 16 chunks x 2 hq = 32 hq per half
    float4 kl[2][2];
#pragma unroll
    for (int i = 0; i < 2; ++i) {     // batched: 4 dwordx4 in flight
      kl[i][0] = kbase[(c * 2 + i) * 32];       // (ek0,ek0,ek1,ek1)
      kl[i][1] = kbase[(c * 2 + i) * 32 + 1];   // (ek2,ek2,ek3,ek3)
    }
#pragma unroll
    for (int i = 0; i < 2; ++i) {
      const int hq = (c * 2 + i) & 31;
      float4 e0 = *(const float4*)&eqt[hb][hq * 4 + 0][0];
      float4 e1 = *(const float4*)&eqt[hb][hq * 4 + 1][0];
      float4 e2 = *(const float4*)&eqt[hb][hq * 4 + 2][0];
      float4 e3 = *(const float4*)&eqt[hb][hq * 4 + 3][0];
      float4 wA = *(const float4*)&wvd[hb][hq * 4 + 0];   // (w0,w0,w1,w1)
      float4 wB = *(const float4*)&wvd[hb][hq * 4 + 2];   // (w2,w2,w3,w3)
      float2v k0 = lo2(kl[i][0]), k1 = hi2(kl[i][0]);
      float2v k2 = lo2(kl[i][1]), k3 = hi2(kl[i][1]);
      // pair A = (q0,q1)
      accA01 = quad_pair(lo2(e0), lo2(e1), lo2(e2), lo2(e3),
                         k0, k1, k2, k3,
                         lo2(wA), hi2(wA), lo2(wB), hi2(wB), accA01);
      // pair B = (q2,q3)
      accA23 = quad_pair(hi2(e0), hi2(e1), hi2(e2), hi2(e3),
                         k0, k1, k2, k3,
                         lo2(wA), hi2(wA), lo2(wB), hi2(wB), accA23);
    }
  }

  if (hb == 1) {
    part[0][t] = accA01.x; part[1][t] = accA01.y;
    part[2][t] = accA23.x; part[3][t] = accA23.y;
  }
  __syncthreads();
  if (hb == 0) {
    const float sumW = *sumWp;
    float* obase = out + ((size_t)(b * 512 + q0)) * 512 + blockIdx.x * 256 + t;
    obase[0]    = sumW + accA01.x + part[0][t];
    obase[512]  = sumW + accA01.y + part[1][t];
    obase[1024] = sumW + accA23.x + part[2][t];
    obase[1536] = sumW + accA23.y + part[3][t];
  }
}

// ---------------------------------------------------------------------------
extern "C" void kernel_launch(void* const* d_in, const int* in_sizes, int n_in,
                              void* d_out, int out_size, void* d_ws, size_t ws_size,
                              hipStream_t stream) {
  (void)in_sizes; (void)n_in; (void)out_size; (void)ws_size;
  const float* queries = (const float*)d_in[0];
  const float* Keys    = (const float*)d_in[1];
  const float* Wq      = (const float*)d_in[2];
  const float* Wk      = (const float*)d_in[3];
  const float* wv      = (const float*)d_in[4];
  float* out = (float*)d_out;

  // ws layout (~11 MB of the 256 MB workspace):
  //   [0, 512K)      Wt   bf16 [2][256][512]
  //   [512K, +1K)    wv2  f32 [256]  (= -2*wv)
  //   [513K, +4)     sumW
  //   [1M, 5M)       Xbf  bf16 [2][2048][512]  (queries||keys, converted)
  //   [5M, 7M)       eq   f32  [2048][256]
  //   [7M, 11M)      ekd  f32  dup pairs [m/16][64][16][4]x(2 f32)
  char* ws = (char*)d_ws;
  __bf16* Wt    = (__bf16*)ws;
  float*  wv2   = (float*)(ws + (512 << 10));
  float*  sumWp = (float*)(ws + (513 << 10));
  __bf16* Xbf   = (__bf16*)(ws + (1 << 20));
  float*  eqp   = (float*)(ws + (5ull << 20));
  float2* ekd   = (float2*)(ws + (7ull << 20));

  prep_kernel<<<dim3(1281), 256, 0, stream>>>(
      Wq, Wk, wv, queries, Keys, Wt, Xbf, wv2, sumWp);
  proj_kernel<<<dim3(64, 8, 2), 256, 0, stream>>>(Xbf, Wt, eqp, ekd);
  score_kernel<<<dim3(2, 128, 4), 512, 0, stream>>>(
      eqp, (const float4*)ekd, wv2, sumWp, out);
}